// Round 11
// baseline (7700.593 us; speedup 1.0000x reference)
//
#include <hip/hip_runtime.h>
#include <math.h>

#define PI_F 3.14159265358979323846f
typedef unsigned long long u64;

// RK stage constants: beta[k], gdt[k]=GAMMA[k]*DT, mu[k]=0.5*DT*(ALPHA[k+1]-ALPHA[k])
__constant__ float c_beta[5] = {0.0f, -0.4178904745f, -1.192151694643f,
                                -1.697784692471f, -1.514183444257f};
__constant__ float c_gdt[5]  = {1.496590219993e-4f, 3.792103129999e-4f,
                                8.229550293869e-4f, 6.994504559488e-4f,
                                1.530572479681e-4f};
__constant__ float c_mu[5]   = {7.482951099965e-5f, 1.1037096768255e-4f,
                                1.2592740288505e-4f, 1.6801318377015e-4f,
                                2.08589346626e-5f};

struct __align__(128) Line { int v; int pad[31]; };

struct SharedMem {
  float sAr[2048], sAi[2048], sBr[2048], sBi[2048];  // [8][256] exchange buffers
  float twr[128], twi[128];
  float t0r[430], t0i[430], t1r[430], t1i[430];      // [86][4] tiles, stride 5
  float t2r[430], t2i[430], t3r[430], t3i[430];
};

// exchange-slot swizzle within a 256-float region: bijective; makes every
// fft_reg write pattern (stride 1/4/16/64) and the tt+64j read pattern land
// exactly 2 lanes/bank (2-way is free on CDNA4).
__device__ __forceinline__ int swz(int i) { return i ^ (i >> 3); }

// ---------------------------------------------------------------------------
// Handoff: plain stores (L2-resident) + relaxed agent loads (L1 bypass).
// ---------------------------------------------------------------------------
__device__ __forceinline__ float2 ldc(const float2* p)
{
  u64 v = __hip_atomic_load((const u64*)p, __ATOMIC_RELAXED, __HIP_MEMORY_SCOPE_AGENT);
  float2 f; __builtin_memcpy(&f, &v, 8); return f;
}
__device__ __forceinline__ void stg(float2* p, float2 f) { *p = f; }

// ---------------------------------------------------------------------------
// Barriers (as rounds 8-10): fast all-poll flag barrier + fenced fallback.
// ---------------------------------------------------------------------------
__device__ __forceinline__ void bar_all(Line* arr, int n, int idx, int gen)
{
  __syncthreads();
  if (threadIdx.x == 0)
    __hip_atomic_store(&arr[idx].v, gen, __ATOMIC_RELAXED, __HIP_MEMORY_SCOPE_AGENT);
  if (threadIdx.x < 64) {
    bool done = false;
    while (!done) {
      bool ok = true;
      for (int w = threadIdx.x; w < n; w += 64)
        if (__hip_atomic_load(&arr[w].v, __ATOMIC_RELAXED, __HIP_MEMORY_SCOPE_AGENT) < gen)
          ok = false;
      done = __all(ok);
      if (!done) __builtin_amdgcn_s_sleep(2);
    }
    __builtin_amdgcn_sched_barrier(0);
  }
  __syncthreads();
}

__device__ __forceinline__ void bar_sync(Line* arr, Line* rel, int n, int idx,
                                         bool lead, int gen, bool fenced)
{
  const int t = threadIdx.x;
  __syncthreads();
  if (t == 0) {
    __builtin_amdgcn_s_waitcnt(0);
    __builtin_amdgcn_sched_barrier(0);
    if (fenced)
      __hip_atomic_store(&arr[idx].v, gen, __ATOMIC_RELEASE, __HIP_MEMORY_SCOPE_AGENT);
    else
      __hip_atomic_store(&arr[idx].v, gen, __ATOMIC_RELAXED, __HIP_MEMORY_SCOPE_AGENT);
  }
  if (lead && t < 64) {
    bool done = false;
    while (!done) {
      bool ok = true;
      for (int w = t; w < n; w += 64)
        if (__hip_atomic_load(&arr[w].v, __ATOMIC_RELAXED, __HIP_MEMORY_SCOPE_AGENT) < gen)
          ok = false;
      done = __all(ok);
      if (!done) __builtin_amdgcn_s_sleep(1);
    }
    __builtin_amdgcn_sched_barrier(0);
    if (fenced)
      (void)__hip_atomic_load(&arr[t & 7].v, __ATOMIC_ACQUIRE, __HIP_MEMORY_SCOPE_AGENT);
    if (t < 8) {
      if (fenced)
        __hip_atomic_store(&rel[t].v, gen, __ATOMIC_RELEASE, __HIP_MEMORY_SCOPE_AGENT);
      else
        __hip_atomic_store(&rel[t].v, gen, __ATOMIC_RELAXED, __HIP_MEMORY_SCOPE_AGENT);
    }
  }
  if (t == 0) {
    Line* f = &rel[idx & 7];
    while (__hip_atomic_load(&f->v, __ATOMIC_RELAXED, __HIP_MEMORY_SCOPE_AGENT) < gen)
      __builtin_amdgcn_s_sleep(1);
    if (fenced)
      (void)__hip_atomic_load(&f->v, __ATOMIC_ACQUIRE, __HIP_MEMORY_SCOPE_AGENT);
    __builtin_amdgcn_sched_barrier(0);
  }
  __syncthreads();
}

// ---------------------------------------------------------------------------
// LDS batched radix-4 Stockham FFT (verified round 9) — init/final only.
// ---------------------------------------------------------------------------
template<int B, bool INVERSE>
__device__ __forceinline__ void fftB(SharedMem& sh, int t)
{
  float *sr = sh.sAr, *si = sh.sAi, *dr = sh.sBr, *di = sh.sBi;
#pragma unroll
  for (int s = 0; s < 8; s += 2) {
    __syncthreads();
    const int m  = 1 << s;
    const int k  = t & (m - 1);
    const int e  = (t >> s) & 1;
    const int p  = (t >> (s + 1)) & 1;
    const int q0 = (t >> (s + 2)) << s;
    const int i0 = q0 + k;
    const float w1r = sh.twr[q0];
    const float w1i = INVERSE ? -sh.twi[q0] : sh.twi[q0];
    const float w2r = sh.twr[q0 << 1];
    const float w2i = INVERSE ? -sh.twi[q0 << 1] : sh.twi[q0 << 1];
#pragma unroll
    for (int f = 0; f < B; ++f) {
      const int base = f * 256;
      float S0r = sr[base + i0],       S0i = si[base + i0];
      float S1r = sr[base + i0 + 128], S1i = si[base + i0 + 128];
      float S2r = sr[base + i0 + 64],  S2i = si[base + i0 + 64];
      float S3r = sr[base + i0 + 192], S3i = si[base + i0 + 192];
      float Ar, Ai, Br, Bi;
      if (e == 0) { Ar = S0r + S1r; Ai = S0i + S1i; Br = S2r + S3r; Bi = S2i + S3i; }
      else {
        float xr = S0r - S1r, xi = S0i - S1i;
        Ar = xr * w1r - xi * w1i; Ai = xr * w1i + xi * w1r;
        float yr = S2r - S3r, yi = S2i - S3i;
        float tr = yr * w1r - yi * w1i, ti = yr * w1i + yi * w1r;
        Br = INVERSE ? -ti : ti; Bi = INVERSE ? tr : -tr;
      }
      float Or, Oi;
      if (p == 0) { Or = Ar + Br; Oi = Ai + Bi; }
      else {
        float xr = Ar - Br, xi = Ai - Bi;
        Or = xr * w2r - xi * w2i; Oi = xr * w2i + xi * w2r;
      }
      dr[base + t] = Or; di[base + t] = Oi;
    }
    float* tp;
    tp = sr; sr = dr; dr = tp;
    tp = si; si = di; di = tp;
  }
  __syncthreads();
}

// radix-4 butterfly on 4 register points (verified round-10 algebra).
// v[0..3] = points at tt+{0,64,128,192}; outputs o[m] go to pos0+(m<<s).
template<bool INVERSE>
__device__ __forceinline__ void bfly4(const float (&vr)[4], const float (&vi)[4],
    float w1r, float w1i, float w2r, float w2i,
    float (&o_r)[4], float (&o_i)[4])
{
  float Ar  = vr[0] + vr[2], Ai  = vi[0] + vi[2];
  float dr_ = vr[0] - vr[2], di_ = vi[0] - vi[2];
  float Atr = dr_ * w1r - di_ * w1i, Ati = dr_ * w1i + di_ * w1r;
  float Br  = vr[1] + vr[3], Bi  = vi[1] + vi[3];
  float er_ = vr[1] - vr[3], ei_ = vi[1] - vi[3];
  float tr_ = er_ * w1r - ei_ * w1i, ti_ = er_ * w1i + ei_ * w1r;
  float Btr = INVERSE ? -ti_ : ti_;
  float Bti = INVERSE ?  tr_ : -tr_;
  o_r[0] = Ar + Br;   o_i[0] = Ai + Bi;
  o_r[1] = Atr + Btr; o_i[1] = Ati + Bti;
  float c0r = Ar - Br,   c0i = Ai - Bi;
  float c1r = Atr - Btr, c1i = Ati - Bti;
  o_r[2] = c0r * w2r - c0i * w2i; o_i[2] = c0r * w2i + c0i * w2r;
  o_r[3] = c1r * w2r - c1i * w2i; o_i[3] = c1r * w2i + c1i * w2r;
}

// ---------------------------------------------------------------------------
// Register radix-4 FFT, single set: 64 thr/transform, 4 pts/thread, B<=4
// transforms (f = t>>6 < B active). Swizzled exchange slots (conflict-free).
// ---------------------------------------------------------------------------
template<int B, bool INVERSE>
__device__ __forceinline__ void fft_reg(SharedMem& sh, int t,
                                        float (&vr)[4], float (&vi)[4])
{
  const int f  = t >> 6;
  const int tt = t & 63;
  const bool act = (f < B);
  __syncthreads();                       // WAR vs prior use of exchange bufs
#pragma unroll
  for (int s4 = 0; s4 < 4; ++s4) {
    const int s = s4 * 2;
    float o_r[4], o_i[4];
    int pos0 = 0;
    if (act) {
      const int k  = tt & ((1 << s) - 1);
      const int q0 = tt - k;
      const float w1r = sh.twr[q0];
      const float w1i = INVERSE ? -sh.twi[q0] : sh.twi[q0];
      const float w2r = sh.twr[q0 << 1];
      const float w2i = INVERSE ? -sh.twi[q0 << 1] : sh.twi[q0 << 1];
      bfly4<INVERSE>(vr, vi, w1r, w1i, w2r, w2i, o_r, o_i);
      pos0 = ((tt >> s) << (s + 2)) + k;
    }
    if (s4 < 3) {
      float* xr = (s4 & 1) ? sh.sBr : sh.sAr;
      float* xi = (s4 & 1) ? sh.sBi : sh.sAi;
      if (act) {
#pragma unroll
        for (int m = 0; m < 4; ++m) {
          const int w_ = f * 256 + swz(pos0 + (m << s));
          xr[w_] = o_r[m]; xi[w_] = o_i[m];
        }
      }
      __syncthreads();
      if (act) {
#pragma unroll
        for (int j = 0; j < 4; ++j) {
          const int rd = f * 256 + swz(tt + 64 * j);
          vr[j] = xr[rd]; vi[j] = xi[rd];
        }
      }
    } else if (act) {
#pragma unroll
      for (int j = 0; j < 4; ++j) { vr[j] = o_r[j]; vi[j] = o_i[j]; }
    }
  }
}

// ---------------------------------------------------------------------------
// Register radix-4 FFT, DUAL: 8 transforms per pass (2 register sets share
// each exchange+sync). Set A at f*256, set B at (f+4)*256. All threads active.
// ---------------------------------------------------------------------------
template<bool INVERSE>
__device__ __forceinline__ void fft_reg_dual(SharedMem& sh, int t,
    float (&ar)[4], float (&ai)[4], float (&br)[4], float (&bi)[4])
{
  const int f  = t >> 6;
  const int tt = t & 63;
  __syncthreads();
#pragma unroll
  for (int s4 = 0; s4 < 4; ++s4) {
    const int s = s4 * 2;
    const int k  = tt & ((1 << s) - 1);
    const int q0 = tt - k;
    const float w1r = sh.twr[q0];
    const float w1i = INVERSE ? -sh.twi[q0] : sh.twi[q0];
    const float w2r = sh.twr[q0 << 1];
    const float w2i = INVERSE ? -sh.twi[q0 << 1] : sh.twi[q0 << 1];
    float oAr[4], oAi[4], oBr[4], oBi[4];
    bfly4<INVERSE>(ar, ai, w1r, w1i, w2r, w2i, oAr, oAi);
    bfly4<INVERSE>(br, bi, w1r, w1i, w2r, w2i, oBr, oBi);
    if (s4 < 3) {
      const int pos0 = ((tt >> s) << (s + 2)) + k;
      float* xr = (s4 & 1) ? sh.sBr : sh.sAr;
      float* xi = (s4 & 1) ? sh.sBi : sh.sAi;
      const int baseA = f * 256, baseB = (f + 4) * 256;
#pragma unroll
      for (int m = 0; m < 4; ++m) {
        const int w_ = swz(pos0 + (m << s));
        xr[baseA + w_] = oAr[m]; xi[baseA + w_] = oAi[m];
        xr[baseB + w_] = oBr[m]; xi[baseB + w_] = oBi[m];
      }
      __syncthreads();
#pragma unroll
      for (int j = 0; j < 4; ++j) {
        const int rd = swz(tt + 64 * j);
        ar[j] = xr[baseA + rd]; ai[j] = xi[baseA + rd];
        br[j] = xr[baseB + rd]; bi[j] = xi[baseB + rd];
      }
    } else {
#pragma unroll
      for (int j = 0; j < 4; ++j) {
        ar[j] = oAr[j]; ai[j] = oAi[j];
        br[j] = oBr[j]; bi[j] = oBi[j];
      }
    }
  }
}

// ---------------------------------------------------------------------------
// Layouts (float2). ky truncated to <=85.
//   u, h : [b][ky][kx]     8*129*256   (plain; same-block producer/consumer)
//   G    : [f][b][ky][x]   4*8*129*256 (handoff)
//   NL1  : [b][ky][x]      8*86*256    (handoff)
//   rec  : [r][b][ky][kx]  3*8*129*256 (handoff; r=0 slab doubles as W1)
// ---------------------------------------------------------------------------

// hermitian-extended input for point n = tt+64j of column f: Z = H0 + i*H1
__device__ __forceinline__ void build_Z2(const float* t0r_, const float* t0i_,
    const float* t1r_, const float* t1i_, int f, int tt,
    float (&zr)[4], float (&zi)[4])
{
#pragma unroll
  for (int j = 0; j < 4; ++j) {
    int n = tt + 64 * j;
    bool low = (n <= 128);
    int kk = low ? n : 256 - n;
    float ar = 0.f, ai = 0.f, br = 0.f, bi = 0.f;
    if (kk <= 85) {
      ar = t0r_[kk * 5 + f]; ai = t0i_[kk * 5 + f];
      br = t1r_[kk * 5 + f]; bi = t1i_[kk * 5 + f];
    }
    zr[j] = low ? (ar - bi) : (ar + bi);
    zi[j] = low ? (ai + br) : (br - ai);
  }
}

// real-space item: 4 x-columns; dual inverse pass + packed forward pass.
__device__ __forceinline__ void real_item4_reg(SharedMem& sh, int t, int b, int x0,
    const float2* __restrict__ G, float2* __restrict__ NL1)
{
  const int f = t >> 6, tt = t & 63;
  __syncthreads();                               // tiles WAR
  for (int i = t; i < 344; i += 256) {           // all 4 fields' tiles
    int ky = i >> 2, xl = i & 3;
    float2 a0 = ldc(&G[(((size_t)0 * 8 + b) * 129 + ky) * 256 + x0 + xl]);
    float2 a1 = ldc(&G[(((size_t)1 * 8 + b) * 129 + ky) * 256 + x0 + xl]);
    float2 a2 = ldc(&G[(((size_t)2 * 8 + b) * 129 + ky) * 256 + x0 + xl]);
    float2 a3 = ldc(&G[(((size_t)3 * 8 + b) * 129 + ky) * 256 + x0 + xl]);
    sh.t0r[ky * 5 + xl] = a0.x; sh.t0i[ky * 5 + xl] = a0.y;
    sh.t1r[ky * 5 + xl] = a1.x; sh.t1i[ky * 5 + xl] = a1.y;
    sh.t2r[ky * 5 + xl] = a2.x; sh.t2i[ky * 5 + xl] = a2.y;
    sh.t3r[ky * 5 + xl] = a3.x; sh.t3i[ky * 5 + xl] = a3.y;
  }
  __syncthreads();
  float ar_[4], ai_[4], br_[4], bi_[4];
  build_Z2(sh.t0r, sh.t0i, sh.t1r, sh.t1i, f, tt, ar_, ai_);  // Hvx + i*Hvy
  build_Z2(sh.t2r, sh.t2i, sh.t3r, sh.t3i, f, tt, br_, bi_);  // Hgx + i*Hgy
  fft_reg_dual<true>(sh, t, ar_, ai_, br_, bi_);
  float nl[4];
#pragma unroll
  for (int j = 0; j < 4; ++j)
    nl[j] = -(ar_[j] * br_[j] + ai_[j] * bi_[j]);   // -(vx*gx + vy*gy)
  __syncthreads();                               // sA WAR vs dual reads
#pragma unroll
  for (int j = 0; j < 4; ++j) sh.sAr[f * 256 + tt + 64 * j] = nl[j];
  __syncthreads();
  float wr2[4], wi2[4];
  if (f < 2) {
#pragma unroll
    for (int j = 0; j < 4; ++j) {
      wr2[j] = sh.sAr[(2 * f) * 256 + tt + 64 * j];
      wi2[j] = sh.sAr[(2 * f + 1) * 256 + tt + 64 * j];
    }
  }
  fft_reg<2, false>(sh, t, wr2, wi2);
  if (f < 2) {
#pragma unroll
    for (int j = 0; j < 4; ++j) {
      sh.sBr[f * 256 + tt + 64 * j] = wr2[j];
      sh.sBi[f * 256 + tt + 64 * j] = wi2[j];
    }
  }
  __syncthreads();
  if (t <= 85) {                                 // hermitian extraction -> NL1
    int mI = (256 - t) & 255;
#pragma unroll
    for (int p = 0; p < 2; ++p) {
      float zr_ = sh.sBr[p * 256 + t],  zi_ = sh.sBi[p * 256 + t];
      float wr_ = sh.sBr[p * 256 + mI], wi_ = sh.sBi[p * 256 + mI];
      stg(&NL1[((size_t)b * 86 + t) * 256 + x0 + 2 * p],
          make_float2(0.5f * (zr_ + wr_), 0.5f * (zi_ - wi_)));
      stg(&NL1[((size_t)b * 86 + t) * 256 + x0 + 2 * p + 1],
          make_float2(0.5f * (zi_ + wi_), 0.5f * (wr_ - zr_)));
    }
  }
}

// spectral item: 2 ky rows (ky0, ky0+1, both <86). fwd B=2 + one dual pass
// covering 4 fields x 2 rows (set A = row0 field f, set B = row1 field f).
__device__ __forceinline__ void spectral_item2_reg(SharedMem& sh, int t, int b, int ky0,
    const float2* __restrict__ NL1, float2* __restrict__ u, float2* __restrict__ h,
    float2* __restrict__ G, float2* __restrict__ rec,
    float beta, float gdt, float mu, bool doUpdate, int recIdx)
{
  const int f = t >> 6, tt = t & 63;
  const size_t r0 = ((size_t)b * 129 + ky0) * 256;

  if (doUpdate) {
    float ar[4], ai[4];
    if (f < 2) {
#pragma unroll
      for (int j = 0; j < 4; ++j) {
        float2 nv = ldc(&NL1[((size_t)b * 86 + ky0 + f) * 256 + tt + 64 * j]);
        ar[j] = nv.x; ai[j] = nv.y;
      }
    }
    fft_reg<2, false>(sh, t, ar, ai);
    if (f < 2) {
      const int ky = ky0 + f;
      const size_t row = r0 + (size_t)f * 256;
#pragma unroll
      for (int j = 0; j < 4; ++j) {
        const int kx = tt + 64 * j;
        const bool keep = (kx < 85) || (kx >= 171);
        float advr = keep ? ar[j] : 0.f;
        float advi = keep ? ai[j] : 0.f;
        if (kx == 0 && ky == 4) {                // forcing f_hat
          float s_, c_;
          __sincosf(PI_F / 64.0f, &s_, &c_);
          advr -= 131072.0f * c_;
          advi -= 131072.0f * s_;
        }
        float hr = advr, hi = advi;
        if (beta != 0.0f) {
          float2 hh = h[row + kx];
          hr += beta * hh.x; hi += beta * hh.y;
        }
        const int jx = (kx < 128) ? kx : kx - 256;
        const float k2   = (float)(jx * jx + ky * ky);
        const float lin  = -0.001f * k2 - 0.1f;
        const float anum = 1.0f + mu * lin;
        const float invd = 1.0f / (1.0f - mu * lin);
        float2 uu = u[row + kx];
        float urv = (uu.x * anum + gdt * hr) * invd;
        float uiv = (uu.y * anum + gdt * hi) * invd;
        u[row + kx] = make_float2(urv, uiv);
        h[row + kx] = make_float2(hr, hi);
        if (recIdx >= 0)
          stg(&rec[((size_t)recIdx * 8 + b) * (129 * 256) + (size_t)ky * 256 + kx],
              make_float2(urv, uiv));
      }
    }
    __syncthreads();   // u stores (same CU L1/L2) visible to whole block
  }

  // all threads: load both rows' updated u at this thread's kx positions
  float u0r[4], u0i[4], u1r[4], u1i[4];
#pragma unroll
  for (int j = 0; j < 4; ++j) {
    float2 a = u[r0 + tt + 64 * j];
    float2 c = u[r0 + 256 + tt + 64 * j];
    u0r[j] = a.x; u0i[j] = a.y; u1r[j] = c.x; u1i[j] = c.y;
  }

  const float NRM = 1.0f / 65536.0f;
  const float fy0 = (float)ky0, fy1 = (float)(ky0 + 1);
  float x0r[4], x0i[4], x1r[4], x1i[4];
#pragma unroll
  for (int j = 0; j < 4; ++j) {
    const int kx = tt + 64 * j;
    const int jx = (kx < 128) ? kx : kx - 256;
    const float fjx = (float)jx;
    {
      const float k2 = (float)(jx * jx + ky0 * ky0);
      const float il = (k2 == 0.f) ? 1.f : (-1.f / k2);
      const float urN = u0r[j] * NRM, uiN = u0i[j] * NRM;
      const float psr = -urN * il, psi_ = -uiN * il;
      if      (f == 0) { x0r[j] = -fy0 * psi_; x0i[j] =  fy0 * psr; }  // vx
      else if (f == 1) { x0r[j] =  fjx * psi_; x0i[j] = -fjx * psr; }  // vy
      else if (f == 2) { x0r[j] = -fjx * uiN;  x0i[j] =  fjx * urN; }  // gx
      else             { x0r[j] = -fy0 * uiN;  x0i[j] =  fy0 * urN; }  // gy
    }
    {
      const int ky1 = ky0 + 1;
      const float k2 = (float)(jx * jx + ky1 * ky1);
      const float il = (k2 == 0.f) ? 1.f : (-1.f / k2);
      const float urN = u1r[j] * NRM, uiN = u1i[j] * NRM;
      const float psr = -urN * il, psi_ = -uiN * il;
      if      (f == 0) { x1r[j] = -fy1 * psi_; x1i[j] =  fy1 * psr; }
      else if (f == 1) { x1r[j] =  fjx * psi_; x1i[j] = -fjx * psr; }
      else if (f == 2) { x1r[j] = -fjx * uiN;  x1i[j] =  fjx * urN; }
      else             { x1r[j] = -fy1 * uiN;  x1i[j] =  fy1 * urN; }
    }
  }
  fft_reg_dual<true>(sh, t, x0r, x0i, x1r, x1i);
#pragma unroll
  for (int j = 0; j < 4; ++j) {
    stg(&G[(((size_t)f * 8 + b) * 129 + ky0) * 256 + tt + 64 * j],
        make_float2(x0r[j], x0i[j]));
    stg(&G[(((size_t)f * 8 + b) * 129 + ky0 + 1) * 256 + tt + 64 * j],
        make_float2(x1r[j], x1i[j]));
  }
}

// ---------------------------------------------------------------------------
// Persistent kernel: per-XCD groups, fast flag barriers, L2-resident handoff.
// ---------------------------------------------------------------------------
__global__ __launch_bounds__(256, 2) void k_persist(
    const float* __restrict__ vort, float* __restrict__ out,
    float2* __restrict__ u, float2* __restrict__ h,
    float2* __restrict__ G, float2* __restrict__ NL1, float2* __restrict__ rec,
    Line* __restrict__ bar)
{
  const int t   = threadIdx.x;
  const int blk = blockIdx.x;
  const int NBg = gridDim.x;

  Line* arrGrid = bar;                    // 1024 lines
  Line* relGrid = bar + 1024;             // 8
  Line* arrGrpA = bar + 1032;             // 8 * 256
  Line* relGrpA = bar + 1032 + 2048;      // 8 * 8
  Line* regL    = bar + 1032 + 2048 + 64; // 16: per-XCD counters

  __shared__ SharedMem sh;
  __shared__ int s_x, s_wi;

  if (t < 128) {
    float s_, c_;
    __sincosf(-(2.0f * PI_F / 256.0f) * (float)t, &s_, &c_);
    sh.twr[t] = c_; sh.twi[t] = s_;
  }

  if (t == 0) {
    int x;
    asm volatile("s_getreg_b32 %0, hwreg(HW_REG_XCC_ID)" : "=s"(x));
    x &= 15;
    s_x  = x;
    s_wi = atomicAdd(&regL[x].v, 1);
  }
  __syncthreads();

  int gen = 0;
  bar_sync(arrGrid, relGrid, NBg, blk, blk == 0, ++gen, true);  // fenced grid bar

  int tot = 0, mn = 1 << 30, mx = 0;
  for (int i = 0; i < 8; ++i) {
    int c = regL[i].v;
    tot += c; mn = min(mn, c); mx = max(mx, c);
  }
  const bool fast = (tot == NBg) && (mn > 0) && (mx <= 256);
  int g, wi, nW;
  if (fast) { g = s_x;     wi = s_wi;     nW = regL[g].v; }
  else      { g = blk & 7; wi = blk >> 3; nW = NBg >> 3;  }
  Line* arr = arrGrpA + g * 256;
  Line* rel = relGrpA + g * 8;
  const bool lead = (wi == 0);

#define GBAR() do { ++gen; if (fast) bar_all(arr, nW, wi, gen); \
                    else bar_sync(arr, rel, nW, wi, lead, gen, true); } while (0)

  // ---- init: rfft along y, 4 x-rows/item packed into 2 complex FFTs ----
  float2* W1 = rec + (size_t)g * (129 * 256);
  for (int w = wi; w < 64; w += nW) {
    const int x0 = w * 4;
#pragma unroll
    for (int p = 0; p < 2; ++p) {
      sh.sAr[p * 256 + t] = vort[((size_t)g * 256 + x0 + 2 * p) * 256 + t];
      sh.sAi[p * 256 + t] = vort[((size_t)g * 256 + x0 + 2 * p + 1) * 256 + t];
    }
    fftB<2, false>(sh, t);
    if (t < 129) {
      int mI = (256 - t) & 255;
#pragma unroll
      for (int p = 0; p < 2; ++p) {
        float zr = sh.sAr[p * 256 + t],  zi = sh.sAi[p * 256 + t];
        float wr = sh.sAr[p * 256 + mI], wi2 = sh.sAi[p * 256 + mI];
        stg(&W1[(size_t)t * 256 + x0 + 2 * p],
            make_float2(0.5f * (zr + wr), 0.5f * (zi - wi2)));
        stg(&W1[(size_t)t * 256 + x0 + 2 * p + 1],
            make_float2(0.5f * (zi + wi2), 0.5f * (wr - zr)));
      }
    }
    __syncthreads();
  }
  GBAR();

  // ---- init: col FFT (W1 -> u) for ky<86, then prepare G ----
  for (int w = wi; w < 43; w += nW) {
    const int ky0 = w * 2;
#pragma unroll
    for (int f = 0; f < 2; ++f) {
      float2 v = ldc(&W1[(size_t)(ky0 + f) * 256 + t]);
      sh.sAr[f * 256 + t] = v.x; sh.sAi[f * 256 + t] = v.y;
    }
    fftB<2, false>(sh, t);
#pragma unroll
    for (int f = 0; f < 2; ++f)
      u[((size_t)g * 129 + ky0 + f) * 256 + t] =
        make_float2(sh.sAr[f * 256 + t], sh.sAi[f * 256 + t]);
  }
  for (int w = wi; w < 43; w += nW)
    spectral_item2_reg(sh, t, g, w * 2, NL1, u, h, G, rec, 0.f, 0.f, 0.f, false, -1);

  // ---- main loop: 90 steps x 5 RK stages ----
  for (int step = 1; step <= 90; ++step) {
    for (int k = 0; k < 5; ++k) {
      GBAR();
      for (int w = wi; w < 64; w += nW)
        real_item4_reg(sh, t, g, w * 4, G, NL1);
      GBAR();
      const int recIdx = (k == 4 && step % 30 == 0) ? (step / 30 - 1) : -1;
      for (int w = wi; w < 43; w += nW)
        spectral_item2_reg(sh, t, g, w * 2, NL1, u, h, G, rec,
                           c_beta[k], c_gdt[k], c_mu[k], true, recIdx);
    }
  }
  GBAR();

  // ---- final: inverse col FFT of records (258 rows, 2 per item) ----
  for (int w = wi; w < 129; w += nW) {
#pragma unroll
    for (int j = 0; j < 2; ++j) {
      int idx = w * 2 + j, r = idx / 86, ky = idx % 86;
      float2 v = ldc(&rec[(((size_t)r * 8 + g) * 129 + ky) * 256 + t]);
      sh.sAr[j * 256 + t] = v.x; sh.sAi[j * 256 + t] = v.y;
    }
    fftB<2, true>(sh, t);
#pragma unroll
    for (int j = 0; j < 2; ++j) {
      int idx = w * 2 + j, r = idx / 86, ky = idx % 86;
      stg(&G[(((size_t)r * 8 + g) * 129 + ky) * 256 + t],
          make_float2(sh.sAr[j * 256 + t], sh.sAi[j * 256 + t]));
    }
  }
  GBAR();

  // ---- final: paired hermitian inverse row FFT -> out (4 cols/item) ----
  const float NRM = 1.0f / 65536.0f;
  for (int w = wi; w < 192; w += nW) {
    const int r = w / 64, xh = w % 64, x0 = xh * 4;
    __syncthreads();
    for (int i = t; i < 344; i += 256) {
      int ky = i >> 2, xl = i & 3;
      float2 a = ldc(&G[(((size_t)r * 8 + g) * 129 + ky) * 256 + x0 + xl]);
      sh.t0r[ky * 5 + xl] = a.x; sh.t0i[ky * 5 + xl] = a.y;
    }
    __syncthreads();
    const bool lower = (t <= 128);
    const int  kk    = lower ? t : 256 - t;
#pragma unroll
    for (int f = 0; f < 2; ++f) {
      float ar = 0.f, ai = 0.f, br = 0.f, bi = 0.f;
      if (kk <= 85) {
        ar = sh.t0r[kk * 5 + 2 * f];     ai = sh.t0i[kk * 5 + 2 * f];
        br = sh.t0r[kk * 5 + 2 * f + 1]; bi = sh.t0i[kk * 5 + 2 * f + 1];
      }
      sh.sAr[f * 256 + t] = lower ? (ar - bi) : (ar + bi);
      sh.sAi[f * 256 + t] = lower ? (ai + br) : (br - ai);
    }
    fftB<2, true>(sh, t);
#pragma unroll
    for (int f = 0; f < 2; ++f) {
      out[((((size_t)r * 8 + g) * 256) + x0 + 2 * f) * 256 + t]     = sh.sAr[f * 256 + t] * NRM;
      out[((((size_t)r * 8 + g) * 256) + x0 + 2 * f + 1) * 256 + t] = sh.sAi[f * 256 + t] * NRM;
    }
    __syncthreads();
  }
#undef GBAR
}

// ---------------------------------------------------------------------------
extern "C" void kernel_launch(void* const* d_in, const int* in_sizes, int n_in,
                              void* d_out, int out_size, void* d_ws, size_t ws_size,
                              hipStream_t stream)
{
  const float* vort = (const float*)d_in[0];
  float* out = (float*)d_out;

  float2* base = (float2*)d_ws;
  float2* u    = base;                 // 8*129*256   = 264192
  float2* h    = u + 264192;           // 264192
  float2* G    = h + 264192;           // 4*8*129*256 = 1056768
  float2* NL1  = G + 1056768;          // 8*86*256    = 176128
  float2* rec  = NL1 + 176128;         // 3*8*129*256 = 792576
  Line*   bar  = (Line*)(rec + 792576);
  const int nLines = 1024 + 8 + 2048 + 64 + 16;   // 3160 lines

  hipMemsetAsync(bar, 0, (size_t)nLines * sizeof(Line), stream);

  int maxPerCU = 0;
  hipOccupancyMaxActiveBlocksPerMultiprocessor(&maxPerCU, k_persist, 256, 0);
  int NBg = maxPerCU * 256;            // 256 CUs on MI355X
  if (NBg <= 0)  NBg = 512;
  if (NBg > 512) NBg = 512;            // 64 blocks/XCD: all busy in real phase
  NBg &= ~63;
  if (NBg < 64)  NBg = 64;

  void* args[] = {(void*)&vort, (void*)&out, (void*)&u, (void*)&h,
                  (void*)&G, (void*)&NL1, (void*)&rec, (void*)&bar};
  hipError_t e = hipLaunchCooperativeKernel(k_persist, dim3(NBg), dim3(256),
                                            args, 0, stream);
  if (e != hipSuccess) {
    hipLaunchKernelGGL(k_persist, dim3(NBg), dim3(256), 0, stream,
                       vort, out, u, h, G, NL1, rec, bar);
  }
}

// Round 12
// 6758.630 us; speedup vs baseline: 1.1394x; 1.1394x over previous
//
#include <hip/hip_runtime.h>
#include <math.h>

#define PI_F 3.14159265358979323846f
typedef unsigned long long u64;

// RK stage constants: beta[k], gdt[k]=GAMMA[k]*DT, mu[k]=0.5*DT*(ALPHA[k+1]-ALPHA[k])
__constant__ float c_beta[5] = {0.0f, -0.4178904745f, -1.192151694643f,
                                -1.697784692471f, -1.514183444257f};
__constant__ float c_gdt[5]  = {1.496590219993e-4f, 3.792103129999e-4f,
                                8.229550293869e-4f, 6.994504559488e-4f,
                                1.530572479681e-4f};
__constant__ float c_mu[5]   = {7.482951099965e-5f, 1.1037096768255e-4f,
                                1.2592740288505e-4f, 1.6801318377015e-4f,
                                2.08589346626e-5f};

struct __align__(128) Line { int v; int pad[31]; };

struct SharedMem {
  float sAr[2048], sAi[2048], sBr[2048], sBi[2048];  // [8][256] exchange regions
  float twr[128], twi[128];
  float t0r[430], t0i[430], t1r[430], t1i[430];      // [86][4] tiles, stride 5
  float t2r[430], t2i[430], t3r[430], t3i[430];
};

// Per-stage exchange-slot swizzle: rotation within each 32-slot block,
// K = 1<<s4. Bijective; write patterns (strides 1/4/16/64) and tt+64j reads
// all land <=2 lanes/bank (2-way is free on CDNA4).
__device__ __forceinline__ int swz(int i, int s4)
{
  return (i & ~31) | ((i + ((i >> 5) << s4)) & 31);
}

// ---------------------------------------------------------------------------
// Handoff: plain stores (L2-resident) + relaxed agent loads (L1 bypass).
// ---------------------------------------------------------------------------
__device__ __forceinline__ float2 ldc(const float2* p)
{
  u64 v = __hip_atomic_load((const u64*)p, __ATOMIC_RELAXED, __HIP_MEMORY_SCOPE_AGENT);
  float2 f; __builtin_memcpy(&f, &v, 8); return f;
}
__device__ __forceinline__ void stg(float2* p, float2 f) { *p = f; }

// ---------------------------------------------------------------------------
// Barriers (as rounds 8-11): fast all-poll flag barrier + fenced fallback.
// ---------------------------------------------------------------------------
__device__ __forceinline__ void bar_all(Line* arr, int n, int idx, int gen)
{
  __syncthreads();
  if (threadIdx.x == 0)
    __hip_atomic_store(&arr[idx].v, gen, __ATOMIC_RELAXED, __HIP_MEMORY_SCOPE_AGENT);
  if (threadIdx.x < 64) {
    bool done = false;
    while (!done) {
      bool ok = true;
      for (int w = threadIdx.x; w < n; w += 64)
        if (__hip_atomic_load(&arr[w].v, __ATOMIC_RELAXED, __HIP_MEMORY_SCOPE_AGENT) < gen)
          ok = false;
      done = __all(ok);
      if (!done) __builtin_amdgcn_s_sleep(2);
    }
    __builtin_amdgcn_sched_barrier(0);
  }
  __syncthreads();
}

__device__ __forceinline__ void bar_sync(Line* arr, Line* rel, int n, int idx,
                                         bool lead, int gen, bool fenced)
{
  const int t = threadIdx.x;
  __syncthreads();
  if (t == 0) {
    __builtin_amdgcn_s_waitcnt(0);
    __builtin_amdgcn_sched_barrier(0);
    if (fenced)
      __hip_atomic_store(&arr[idx].v, gen, __ATOMIC_RELEASE, __HIP_MEMORY_SCOPE_AGENT);
    else
      __hip_atomic_store(&arr[idx].v, gen, __ATOMIC_RELAXED, __HIP_MEMORY_SCOPE_AGENT);
  }
  if (lead && t < 64) {
    bool done = false;
    while (!done) {
      bool ok = true;
      for (int w = t; w < n; w += 64)
        if (__hip_atomic_load(&arr[w].v, __ATOMIC_RELAXED, __HIP_MEMORY_SCOPE_AGENT) < gen)
          ok = false;
      done = __all(ok);
      if (!done) __builtin_amdgcn_s_sleep(1);
    }
    __builtin_amdgcn_sched_barrier(0);
    if (fenced)
      (void)__hip_atomic_load(&arr[t & 7].v, __ATOMIC_ACQUIRE, __HIP_MEMORY_SCOPE_AGENT);
    if (t < 8) {
      if (fenced)
        __hip_atomic_store(&rel[t].v, gen, __ATOMIC_RELEASE, __HIP_MEMORY_SCOPE_AGENT);
      else
        __hip_atomic_store(&rel[t].v, gen, __ATOMIC_RELAXED, __HIP_MEMORY_SCOPE_AGENT);
    }
  }
  if (t == 0) {
    Line* f = &rel[idx & 7];
    while (__hip_atomic_load(&f->v, __ATOMIC_RELAXED, __HIP_MEMORY_SCOPE_AGENT) < gen)
      __builtin_amdgcn_s_sleep(1);
    if (fenced)
      (void)__hip_atomic_load(&f->v, __ATOMIC_ACQUIRE, __HIP_MEMORY_SCOPE_AGENT);
    __builtin_amdgcn_sched_barrier(0);
  }
  __syncthreads();
}

// ---------------------------------------------------------------------------
// LDS batched radix-4 Stockham FFT (verified round 9) — init/final only.
// (Cross-wave batching: keeps its __syncthreads.)
// ---------------------------------------------------------------------------
template<int B, bool INVERSE>
__device__ __forceinline__ void fftB(SharedMem& sh, int t)
{
  float *sr = sh.sAr, *si = sh.sAi, *dr = sh.sBr, *di = sh.sBi;
#pragma unroll
  for (int s = 0; s < 8; s += 2) {
    __syncthreads();
    const int m  = 1 << s;
    const int k  = t & (m - 1);
    const int e  = (t >> s) & 1;
    const int p  = (t >> (s + 1)) & 1;
    const int q0 = (t >> (s + 2)) << s;
    const int i0 = q0 + k;
    const float w1r = sh.twr[q0];
    const float w1i = INVERSE ? -sh.twi[q0] : sh.twi[q0];
    const float w2r = sh.twr[q0 << 1];
    const float w2i = INVERSE ? -sh.twi[q0 << 1] : sh.twi[q0 << 1];
#pragma unroll
    for (int f = 0; f < B; ++f) {
      const int base = f * 256;
      float S0r = sr[base + i0],       S0i = si[base + i0];
      float S1r = sr[base + i0 + 128], S1i = si[base + i0 + 128];
      float S2r = sr[base + i0 + 64],  S2i = si[base + i0 + 64];
      float S3r = sr[base + i0 + 192], S3i = si[base + i0 + 192];
      float Ar, Ai, Br, Bi;
      if (e == 0) { Ar = S0r + S1r; Ai = S0i + S1i; Br = S2r + S3r; Bi = S2i + S3i; }
      else {
        float xr = S0r - S1r, xi = S0i - S1i;
        Ar = xr * w1r - xi * w1i; Ai = xr * w1i + xi * w1r;
        float yr = S2r - S3r, yi = S2i - S3i;
        float tr = yr * w1r - yi * w1i, ti = yr * w1i + yi * w1r;
        Br = INVERSE ? -ti : ti; Bi = INVERSE ? tr : -tr;
      }
      float Or, Oi;
      if (p == 0) { Or = Ar + Br; Oi = Ai + Bi; }
      else {
        float xr = Ar - Br, xi = Ai - Bi;
        Or = xr * w2r - xi * w2i; Oi = xr * w2i + xi * w2r;
      }
      dr[base + t] = Or; di[base + t] = Oi;
    }
    float* tp;
    tp = sr; sr = dr; dr = tp;
    tp = si; si = di; di = tp;
  }
  __syncthreads();
}

// radix-4 butterfly on 4 register points (verified round-10/11 algebra).
template<bool INVERSE>
__device__ __forceinline__ void bfly4(const float (&vr)[4], const float (&vi)[4],
    float w1r, float w1i, float w2r, float w2i,
    float (&o_r)[4], float (&o_i)[4])
{
  float Ar  = vr[0] + vr[2], Ai  = vi[0] + vi[2];
  float dr_ = vr[0] - vr[2], di_ = vi[0] - vi[2];
  float Atr = dr_ * w1r - di_ * w1i, Ati = dr_ * w1i + di_ * w1r;
  float Br  = vr[1] + vr[3], Bi  = vi[1] + vi[3];
  float er_ = vr[1] - vr[3], ei_ = vi[1] - vi[3];
  float tr_ = er_ * w1r - ei_ * w1i, ti_ = er_ * w1i + ei_ * w1r;
  float Btr = INVERSE ? -ti_ : ti_;
  float Bti = INVERSE ?  tr_ : -tr_;
  o_r[0] = Ar + Br;   o_i[0] = Ai + Bi;
  o_r[1] = Atr + Btr; o_i[1] = Ati + Bti;
  float c0r = Ar - Br,   c0i = Ai - Bi;
  float c1r = Atr - Btr, c1i = Ati - Bti;
  o_r[2] = c0r * w2r - c0i * w2i; o_i[2] = c0r * w2i + c0i * w2r;
  o_r[3] = c1r * w2r - c1i * w2i; o_i[3] = c1r * w2i + c1i * w2r;
}

// ---------------------------------------------------------------------------
// Register radix-4 FFT, single set: 64 thr/transform, 4 pts/thread.
// Exchange regions are WAVE-PRIVATE (region f+RO for wave f) -> the exchange
// is intra-wave: in-order per-wave DS pipe + lgkmcnt orders write->read.
// ZERO __syncthreads. Inactive waves (f>=B) return immediately.
// ---------------------------------------------------------------------------
template<int B, bool INVERSE, int RO>
__device__ __forceinline__ void fft_reg(SharedMem& sh, int t,
                                        float (&vr)[4], float (&vi)[4])
{
  const int f  = t >> 6;
  const int tt = t & 63;
  if (f >= B) return;
  const int base = (f + RO) * 256;
#pragma unroll
  for (int s4 = 0; s4 < 4; ++s4) {
    const int s = s4 * 2;
    const int k  = tt & ((1 << s) - 1);
    const int q0 = tt - k;
    const float w1r = sh.twr[q0];
    const float w1i = INVERSE ? -sh.twi[q0] : sh.twi[q0];
    const float w2r = sh.twr[q0 << 1];
    const float w2i = INVERSE ? -sh.twi[q0 << 1] : sh.twi[q0 << 1];
    float o_r[4], o_i[4];
    bfly4<INVERSE>(vr, vi, w1r, w1i, w2r, w2i, o_r, o_i);
    if (s4 < 3) {
      const int pos0 = ((tt >> s) << (s + 2)) + k;
      float* xr = (s4 & 1) ? sh.sBr : sh.sAr;
      float* xi = (s4 & 1) ? sh.sBi : sh.sAi;
#pragma unroll
      for (int m = 0; m < 4; ++m) {
        const int w_ = base + swz(pos0 + (m << s), s4);
        xr[w_] = o_r[m]; xi[w_] = o_i[m];
      }
#pragma unroll
      for (int j = 0; j < 4; ++j) {
        const int rd = base + swz(tt + 64 * j, s4);
        vr[j] = xr[rd]; vi[j] = xi[rd];
      }
    } else {
#pragma unroll
      for (int j = 0; j < 4; ++j) { vr[j] = o_r[j]; vi[j] = o_i[j]; }
    }
  }
}

// ---------------------------------------------------------------------------
// Register radix-4 FFT, DUAL: 8 transforms (2 sets), regions f and f+4 —
// both wave-private. ZERO __syncthreads.
// ---------------------------------------------------------------------------
template<bool INVERSE>
__device__ __forceinline__ void fft_reg_dual(SharedMem& sh, int t,
    float (&ar)[4], float (&ai)[4], float (&br)[4], float (&bi)[4])
{
  const int f  = t >> 6;
  const int tt = t & 63;
  const int baseA = f * 256, baseB = (f + 4) * 256;
#pragma unroll
  for (int s4 = 0; s4 < 4; ++s4) {
    const int s = s4 * 2;
    const int k  = tt & ((1 << s) - 1);
    const int q0 = tt - k;
    const float w1r = sh.twr[q0];
    const float w1i = INVERSE ? -sh.twi[q0] : sh.twi[q0];
    const float w2r = sh.twr[q0 << 1];
    const float w2i = INVERSE ? -sh.twi[q0 << 1] : sh.twi[q0 << 1];
    float oAr[4], oAi[4], oBr[4], oBi[4];
    bfly4<INVERSE>(ar, ai, w1r, w1i, w2r, w2i, oAr, oAi);
    bfly4<INVERSE>(br, bi, w1r, w1i, w2r, w2i, oBr, oBi);
    if (s4 < 3) {
      const int pos0 = ((tt >> s) << (s + 2)) + k;
      float* xr = (s4 & 1) ? sh.sBr : sh.sAr;
      float* xi = (s4 & 1) ? sh.sBi : sh.sAi;
#pragma unroll
      for (int m = 0; m < 4; ++m) {
        const int w_ = swz(pos0 + (m << s), s4);
        xr[baseA + w_] = oAr[m]; xi[baseA + w_] = oAi[m];
        xr[baseB + w_] = oBr[m]; xi[baseB + w_] = oBi[m];
      }
#pragma unroll
      for (int j = 0; j < 4; ++j) {
        const int rd = swz(tt + 64 * j, s4);
        ar[j] = xr[baseA + rd]; ai[j] = xi[baseA + rd];
        br[j] = xr[baseB + rd]; bi[j] = xi[baseB + rd];
      }
    } else {
#pragma unroll
      for (int j = 0; j < 4; ++j) {
        ar[j] = oAr[j]; ai[j] = oAi[j];
        br[j] = oBr[j]; bi[j] = oBi[j];
      }
    }
  }
}

// ---------------------------------------------------------------------------
// Layouts (float2). ky truncated to <=85.
//   u, h : [b][ky][kx]     8*129*256   (plain; same-block producer/consumer)
//   G    : [f][b][ky][x]   4*8*129*256 (handoff)
//   NL1  : [b][ky][x]      8*86*256    (handoff)
//   rec  : [r][b][ky][kx]  3*8*129*256 (handoff; r=0 slab doubles as W1)
// ---------------------------------------------------------------------------

// hermitian-extended input for point n = tt+64j of column f: Z = H0 + i*H1
__device__ __forceinline__ void build_Z2(const float* t0r_, const float* t0i_,
    const float* t1r_, const float* t1i_, int f, int tt,
    float (&zr)[4], float (&zi)[4])
{
#pragma unroll
  for (int j = 0; j < 4; ++j) {
    int n = tt + 64 * j;
    bool low = (n <= 128);
    int kk = low ? n : 256 - n;
    float ar = 0.f, ai = 0.f, br = 0.f, bi = 0.f;
    if (kk <= 85) {
      ar = t0r_[kk * 5 + f]; ai = t0i_[kk * 5 + f];
      br = t1r_[kk * 5 + f]; bi = t1i_[kk * 5 + f];
    }
    zr[j] = low ? (ar - bi) : (ar + bi);
    zi[j] = low ? (ai + br) : (br - ai);
  }
}

// real-space item: 4 x-columns; dual inverse pass + packed forward pass.
// Cross-wave syncs ONLY at: tile ready, nl pack -> wr2 read, sBr stage -> extract.
__device__ __forceinline__ void real_item4_reg(SharedMem& sh, int t, int b, int x0,
    const float2* __restrict__ G, float2* __restrict__ NL1)
{
  const int f = t >> 6, tt = t & 63;
  for (int i = t; i < 344; i += 256) {           // all 4 fields' tiles
    int ky = i >> 2, xl = i & 3;
    float2 a0 = ldc(&G[(((size_t)0 * 8 + b) * 129 + ky) * 256 + x0 + xl]);
    float2 a1 = ldc(&G[(((size_t)1 * 8 + b) * 129 + ky) * 256 + x0 + xl]);
    float2 a2 = ldc(&G[(((size_t)2 * 8 + b) * 129 + ky) * 256 + x0 + xl]);
    float2 a3 = ldc(&G[(((size_t)3 * 8 + b) * 129 + ky) * 256 + x0 + xl]);
    sh.t0r[ky * 5 + xl] = a0.x; sh.t0i[ky * 5 + xl] = a0.y;
    sh.t1r[ky * 5 + xl] = a1.x; sh.t1i[ky * 5 + xl] = a1.y;
    sh.t2r[ky * 5 + xl] = a2.x; sh.t2i[ky * 5 + xl] = a2.y;
    sh.t3r[ky * 5 + xl] = a3.x; sh.t3i[ky * 5 + xl] = a3.y;
  }
  __syncthreads();
  float ar_[4], ai_[4], br_[4], bi_[4];
  build_Z2(sh.t0r, sh.t0i, sh.t1r, sh.t1i, f, tt, ar_, ai_);  // Hvx + i*Hvy
  build_Z2(sh.t2r, sh.t2i, sh.t3r, sh.t3i, f, tt, br_, bi_);  // Hgx + i*Hgy
  fft_reg_dual<true>(sh, t, ar_, ai_, br_, bi_);
  float nl[4];
#pragma unroll
  for (int j = 0; j < 4; ++j)
    nl[j] = -(ar_[j] * br_[j] + ai_[j] * bi_[j]);   // -(vx*gx + vy*gy)
  // pack nl into sAr regions 0..3 (wave-private write; cross-wave read next)
#pragma unroll
  for (int j = 0; j < 4; ++j) sh.sAr[f * 256 + tt + 64 * j] = nl[j];
  __syncthreads();
  float wr2[4], wi2[4];
  if (f < 2) {
#pragma unroll
    for (int j = 0; j < 4; ++j) {
      wr2[j] = sh.sAr[(2 * f) * 256 + tt + 64 * j];
      wi2[j] = sh.sAr[(2 * f + 1) * 256 + tt + 64 * j];
    }
  }
  fft_reg<2, false, 4>(sh, t, wr2, wi2);     // regions 4,5: intra-wave WAR only
  if (f < 2) {
#pragma unroll
    for (int j = 0; j < 4; ++j) {
      sh.sBr[f * 256 + tt + 64 * j] = wr2[j];
      sh.sBi[f * 256 + tt + 64 * j] = wi2[j];
    }
  }
  __syncthreads();
  if (t <= 85) {                                 // hermitian extraction -> NL1
    int mI = (256 - t) & 255;
#pragma unroll
    for (int p = 0; p < 2; ++p) {
      float zr_ = sh.sBr[p * 256 + t],  zi_ = sh.sBi[p * 256 + t];
      float wr_ = sh.sBr[p * 256 + mI], wi_ = sh.sBi[p * 256 + mI];
      stg(&NL1[((size_t)b * 86 + t) * 256 + x0 + 2 * p],
          make_float2(0.5f * (zr_ + wr_), 0.5f * (zi_ - wi_)));
      stg(&NL1[((size_t)b * 86 + t) * 256 + x0 + 2 * p + 1],
          make_float2(0.5f * (zi_ + wi_), 0.5f * (wr_ - zr_)));
    }
  }
}

// spectral item: 2 ky rows. fwd B=2 + one dual pass (4 fields x 2 rows).
// One cross-wave sync (u update -> all-wave read).
__device__ __forceinline__ void spectral_item2_reg(SharedMem& sh, int t, int b, int ky0,
    const float2* __restrict__ NL1, float2* __restrict__ u, float2* __restrict__ h,
    float2* __restrict__ G, float2* __restrict__ rec,
    float beta, float gdt, float mu, bool doUpdate, int recIdx)
{
  const int f = t >> 6, tt = t & 63;
  const size_t r0 = ((size_t)b * 129 + ky0) * 256;

  if (doUpdate) {
    float ar[4], ai[4];
    if (f < 2) {
#pragma unroll
      for (int j = 0; j < 4; ++j) {
        float2 nv = ldc(&NL1[((size_t)b * 86 + ky0 + f) * 256 + tt + 64 * j]);
        ar[j] = nv.x; ai[j] = nv.y;
      }
    }
    fft_reg<2, false, 0>(sh, t, ar, ai);
    if (f < 2) {
      const int ky = ky0 + f;
      const size_t row = r0 + (size_t)f * 256;
#pragma unroll
      for (int j = 0; j < 4; ++j) {
        const int kx = tt + 64 * j;
        const bool keep = (kx < 85) || (kx >= 171);
        float advr = keep ? ar[j] : 0.f;
        float advi = keep ? ai[j] : 0.f;
        if (kx == 0 && ky == 4) {                // forcing f_hat
          float s_, c_;
          __sincosf(PI_F / 64.0f, &s_, &c_);
          advr -= 131072.0f * c_;
          advi -= 131072.0f * s_;
        }
        float hr = advr, hi = advi;
        if (beta != 0.0f) {
          float2 hh = h[row + kx];
          hr += beta * hh.x; hi += beta * hh.y;
        }
        const int jx = (kx < 128) ? kx : kx - 256;
        const float k2   = (float)(jx * jx + ky * ky);
        const float lin  = -0.001f * k2 - 0.1f;
        const float anum = 1.0f + mu * lin;
        const float invd = 1.0f / (1.0f - mu * lin);
        float2 uu = u[row + kx];
        float urv = (uu.x * anum + gdt * hr) * invd;
        float uiv = (uu.y * anum + gdt * hi) * invd;
        u[row + kx] = make_float2(urv, uiv);
        h[row + kx] = make_float2(hr, hi);
        if (recIdx >= 0)
          stg(&rec[((size_t)recIdx * 8 + b) * (129 * 256) + (size_t)ky * 256 + kx],
              make_float2(urv, uiv));
      }
    }
    __syncthreads();   // u stores visible + order fwd's LDS use before dual
  }

  // all threads: load both rows' updated u at this thread's kx positions
  float u0r[4], u0i[4], u1r[4], u1i[4];
#pragma unroll
  for (int j = 0; j < 4; ++j) {
    float2 a = u[r0 + tt + 64 * j];
    float2 c = u[r0 + 256 + tt + 64 * j];
    u0r[j] = a.x; u0i[j] = a.y; u1r[j] = c.x; u1i[j] = c.y;
  }

  const float NRM = 1.0f / 65536.0f;
  const float fy0 = (float)ky0, fy1 = (float)(ky0 + 1);
  float x0r[4], x0i[4], x1r[4], x1i[4];
#pragma unroll
  for (int j = 0; j < 4; ++j) {
    const int kx = tt + 64 * j;
    const int jx = (kx < 128) ? kx : kx - 256;
    const float fjx = (float)jx;
    {
      const float k2 = (float)(jx * jx + ky0 * ky0);
      const float il = (k2 == 0.f) ? 1.f : (-1.f / k2);
      const float urN = u0r[j] * NRM, uiN = u0i[j] * NRM;
      const float psr = -urN * il, psi_ = -uiN * il;
      if      (f == 0) { x0r[j] = -fy0 * psi_; x0i[j] =  fy0 * psr; }  // vx
      else if (f == 1) { x0r[j] =  fjx * psi_; x0i[j] = -fjx * psr; }  // vy
      else if (f == 2) { x0r[j] = -fjx * uiN;  x0i[j] =  fjx * urN; }  // gx
      else             { x0r[j] = -fy0 * uiN;  x0i[j] =  fy0 * urN; }  // gy
    }
    {
      const int ky1 = ky0 + 1;
      const float k2 = (float)(jx * jx + ky1 * ky1);
      const float il = (k2 == 0.f) ? 1.f : (-1.f / k2);
      const float urN = u1r[j] * NRM, uiN = u1i[j] * NRM;
      const float psr = -urN * il, psi_ = -uiN * il;
      if      (f == 0) { x1r[j] = -fy1 * psi_; x1i[j] =  fy1 * psr; }
      else if (f == 1) { x1r[j] =  fjx * psi_; x1i[j] = -fjx * psr; }
      else if (f == 2) { x1r[j] = -fjx * uiN;  x1i[j] =  fjx * urN; }
      else             { x1r[j] = -fy1 * uiN;  x1i[j] =  fy1 * urN; }
    }
  }
  fft_reg_dual<true>(sh, t, x0r, x0i, x1r, x1i);
#pragma unroll
  for (int j = 0; j < 4; ++j) {
    stg(&G[(((size_t)f * 8 + b) * 129 + ky0) * 256 + tt + 64 * j],
        make_float2(x0r[j], x0i[j]));
    stg(&G[(((size_t)f * 8 + b) * 129 + ky0 + 1) * 256 + tt + 64 * j],
        make_float2(x1r[j], x1i[j]));
  }
}

// ---------------------------------------------------------------------------
// Persistent kernel: per-XCD groups, fast flag barriers, L2-resident handoff.
// ---------------------------------------------------------------------------
__global__ __launch_bounds__(256, 2) void k_persist(
    const float* __restrict__ vort, float* __restrict__ out,
    float2* __restrict__ u, float2* __restrict__ h,
    float2* __restrict__ G, float2* __restrict__ NL1, float2* __restrict__ rec,
    Line* __restrict__ bar)
{
  const int t   = threadIdx.x;
  const int blk = blockIdx.x;
  const int NBg = gridDim.x;

  Line* arrGrid = bar;                    // 1024 lines
  Line* relGrid = bar + 1024;             // 8
  Line* arrGrpA = bar + 1032;             // 8 * 256
  Line* relGrpA = bar + 1032 + 2048;      // 8 * 8
  Line* regL    = bar + 1032 + 2048 + 64; // 16: per-XCD counters

  __shared__ SharedMem sh;
  __shared__ int s_x, s_wi;

  if (t < 128) {
    float s_, c_;
    __sincosf(-(2.0f * PI_F / 256.0f) * (float)t, &s_, &c_);
    sh.twr[t] = c_; sh.twi[t] = s_;
  }

  if (t == 0) {
    int x;
    asm volatile("s_getreg_b32 %0, hwreg(HW_REG_XCC_ID)" : "=s"(x));
    x &= 15;
    s_x  = x;
    s_wi = atomicAdd(&regL[x].v, 1);
  }
  __syncthreads();

  int gen = 0;
  bar_sync(arrGrid, relGrid, NBg, blk, blk == 0, ++gen, true);  // fenced grid bar

  int tot = 0, mn = 1 << 30, mx = 0;
  for (int i = 0; i < 8; ++i) {
    int c = regL[i].v;
    tot += c; mn = min(mn, c); mx = max(mx, c);
  }
  const bool fast = (tot == NBg) && (mn > 0) && (mx <= 256);
  int g, wi, nW;
  if (fast) { g = s_x;     wi = s_wi;     nW = regL[g].v; }
  else      { g = blk & 7; wi = blk >> 3; nW = NBg >> 3;  }
  Line* arr = arrGrpA + g * 256;
  Line* rel = relGrpA + g * 8;
  const bool lead = (wi == 0);

#define GBAR() do { ++gen; if (fast) bar_all(arr, nW, wi, gen); \
                    else bar_sync(arr, rel, nW, wi, lead, gen, true); } while (0)

  // ---- init: rfft along y, 4 x-rows/item packed into 2 complex FFTs ----
  float2* W1 = rec + (size_t)g * (129 * 256);
  for (int w = wi; w < 64; w += nW) {
    const int x0 = w * 4;
#pragma unroll
    for (int p = 0; p < 2; ++p) {
      sh.sAr[p * 256 + t] = vort[((size_t)g * 256 + x0 + 2 * p) * 256 + t];
      sh.sAi[p * 256 + t] = vort[((size_t)g * 256 + x0 + 2 * p + 1) * 256 + t];
    }
    fftB<2, false>(sh, t);
    if (t < 129) {
      int mI = (256 - t) & 255;
#pragma unroll
      for (int p = 0; p < 2; ++p) {
        float zr = sh.sAr[p * 256 + t],  zi = sh.sAi[p * 256 + t];
        float wr = sh.sAr[p * 256 + mI], wi2 = sh.sAi[p * 256 + mI];
        stg(&W1[(size_t)t * 256 + x0 + 2 * p],
            make_float2(0.5f * (zr + wr), 0.5f * (zi - wi2)));
        stg(&W1[(size_t)t * 256 + x0 + 2 * p + 1],
            make_float2(0.5f * (zi + wi2), 0.5f * (wr - zr)));
      }
    }
    __syncthreads();
  }
  GBAR();

  // ---- init: col FFT (W1 -> u) for ky<86, then prepare G ----
  for (int w = wi; w < 43; w += nW) {
    const int ky0 = w * 2;
#pragma unroll
    for (int f = 0; f < 2; ++f) {
      float2 v = ldc(&W1[(size_t)(ky0 + f) * 256 + t]);
      sh.sAr[f * 256 + t] = v.x; sh.sAi[f * 256 + t] = v.y;
    }
    fftB<2, false>(sh, t);
#pragma unroll
    for (int f = 0; f < 2; ++f)
      u[((size_t)g * 129 + ky0 + f) * 256 + t] =
        make_float2(sh.sAr[f * 256 + t], sh.sAi[f * 256 + t]);
  }
  __syncthreads();   // fftB cross-wave reads of sA done before prepare's writes
  for (int w = wi; w < 43; w += nW)
    spectral_item2_reg(sh, t, g, w * 2, NL1, u, h, G, rec, 0.f, 0.f, 0.f, false, -1);

  // ---- main loop: 90 steps x 5 RK stages ----
  for (int step = 1; step <= 90; ++step) {
    for (int k = 0; k < 5; ++k) {
      GBAR();
      for (int w = wi; w < 64; w += nW)
        real_item4_reg(sh, t, g, w * 4, G, NL1);
      GBAR();
      const int recIdx = (k == 4 && step % 30 == 0) ? (step / 30 - 1) : -1;
      for (int w = wi; w < 43; w += nW)
        spectral_item2_reg(sh, t, g, w * 2, NL1, u, h, G, rec,
                           c_beta[k], c_gdt[k], c_mu[k], true, recIdx);
    }
  }
  GBAR();

  // ---- final: inverse col FFT of records (258 rows, 2 per item) ----
  for (int w = wi; w < 129; w += nW) {
#pragma unroll
    for (int j = 0; j < 2; ++j) {
      int idx = w * 2 + j, r = idx / 86, ky = idx % 86;
      float2 v = ldc(&rec[(((size_t)r * 8 + g) * 129 + ky) * 256 + t]);
      sh.sAr[j * 256 + t] = v.x; sh.sAi[j * 256 + t] = v.y;
    }
    fftB<2, true>(sh, t);
#pragma unroll
    for (int j = 0; j < 2; ++j) {
      int idx = w * 2 + j, r = idx / 86, ky = idx % 86;
      stg(&G[(((size_t)r * 8 + g) * 129 + ky) * 256 + t],
          make_float2(sh.sAr[j * 256 + t], sh.sAi[j * 256 + t]));
    }
    __syncthreads();
  }
  GBAR();

  // ---- final: paired hermitian inverse row FFT -> out (4 cols/item) ----
  const float NRM = 1.0f / 65536.0f;
  for (int w = wi; w < 192; w += nW) {
    const int r = w / 64, xh = w % 64, x0 = xh * 4;
    __syncthreads();
    for (int i = t; i < 344; i += 256) {
      int ky = i >> 2, xl = i & 3;
      float2 a = ldc(&G[(((size_t)r * 8 + g) * 129 + ky) * 256 + x0 + xl]);
      sh.t0r[ky * 5 + xl] = a.x; sh.t0i[ky * 5 + xl] = a.y;
    }
    __syncthreads();
    const bool lower = (t <= 128);
    const int  kk    = lower ? t : 256 - t;
#pragma unroll
    for (int f = 0; f < 2; ++f) {
      float ar = 0.f, ai = 0.f, br = 0.f, bi = 0.f;
      if (kk <= 85) {
        ar = sh.t0r[kk * 5 + 2 * f];     ai = sh.t0i[kk * 5 + 2 * f];
        br = sh.t0r[kk * 5 + 2 * f + 1]; bi = sh.t0i[kk * 5 + 2 * f + 1];
      }
      sh.sAr[f * 256 + t] = lower ? (ar - bi) : (ar + bi);
      sh.sAi[f * 256 + t] = lower ? (ai + br) : (br - ai);
    }
    fftB<2, true>(sh, t);
#pragma unroll
    for (int f = 0; f < 2; ++f) {
      out[((((size_t)r * 8 + g) * 256) + x0 + 2 * f) * 256 + t]     = sh.sAr[f * 256 + t] * NRM;
      out[((((size_t)r * 8 + g) * 256) + x0 + 2 * f + 1) * 256 + t] = sh.sAi[f * 256 + t] * NRM;
    }
    __syncthreads();
  }
#undef GBAR
}

// ---------------------------------------------------------------------------
extern "C" void kernel_launch(void* const* d_in, const int* in_sizes, int n_in,
                              void* d_out, int out_size, void* d_ws, size_t ws_size,
                              hipStream_t stream)
{
  const float* vort = (const float*)d_in[0];
  float* out = (float*)d_out;

  float2* base = (float2*)d_ws;
  float2* u    = base;                 // 8*129*256   = 264192
  float2* h    = u + 264192;           // 264192
  float2* G    = h + 264192;           // 4*8*129*256 = 1056768
  float2* NL1  = G + 1056768;          // 8*86*256    = 176128
  float2* rec  = NL1 + 176128;         // 3*8*129*256 = 792576
  Line*   bar  = (Line*)(rec + 792576);
  const int nLines = 1024 + 8 + 2048 + 64 + 16;   // 3160 lines

  hipMemsetAsync(bar, 0, (size_t)nLines * sizeof(Line), stream);

  int maxPerCU = 0;
  hipOccupancyMaxActiveBlocksPerMultiprocessor(&maxPerCU, k_persist, 256, 0);
  int NBg = maxPerCU * 256;            // 256 CUs on MI355X
  if (NBg <= 0)  NBg = 512;
  if (NBg > 512) NBg = 512;            // 64 blocks/XCD: all busy in real phase
  NBg &= ~63;
  if (NBg < 64)  NBg = 64;

  void* args[] = {(void*)&vort, (void*)&out, (void*)&u, (void*)&h,
                  (void*)&G, (void*)&NL1, (void*)&rec, (void*)&bar};
  hipError_t e = hipLaunchCooperativeKernel(k_persist, dim3(NBg), dim3(256),
                                            args, 0, stream);
  if (e != hipSuccess) {
    hipLaunchKernelGGL(k_persist, dim3(NBg), dim3(256), 0, stream,
                       vort, out, u, h, G, NL1, rec, bar);
  }
}